// Round 2
// baseline (17.109 us; speedup 1.0000x reference)
//
#include <hip/hip_runtime.h>
#include <hip/hip_bf16.h>

// Antialiased bilinear resize (2,3,345,456) -> (2,3,271,272), fp32, two-phase:
//   K1: compute all 272 x-weight sets + 271 y-weight sets (normalized, masked)
//       into d_ws — exact fdiv, matches aten decomposition numerics.
//   K2: pure gather: each thread reads its (wx,xmin)/(wy,ymin) rows as two
//       float4s and does the 5x5 clamped gather + horizontal-then-vertical FMA.

#define IW 456
#define IH 345
#define OW 272
#define OH 271
#define BC 6            // batch*channels = 2*3
#define KS 5

// ws layout: 8 floats per entry {w0..w4, min(bitcast int), pad, pad}
//   x table: entries [0, OW)    at ws + ox*8
//   y table: entries [0, OH)    at ws + (OW + oy)*8
#define XTAB(o)  ((o) * 8)
#define YTAB(o)  ((OW + (o)) * 8)

__global__ __launch_bounds__(576) void weights_kernel(float* __restrict__ ws)
{
    int t = threadIdx.x;   // single block of 576 covers 272+271=543 entries
    float scale, invscale;
    int in_size, base_off, o;
    if (t < OW) {
        o = t; in_size = IW;
        scale = (float)IW / (float)OW; invscale = (float)OW / (float)IW;
        base_off = XTAB(o);
    } else if (t < OW + OH) {
        o = t - OW; in_size = IH;
        scale = (float)IH / (float)OH; invscale = (float)OH / (float)IH;
        base_off = YTAB(o);
    } else {
        return;
    }

    float c = ((float)o + 0.5f) * scale;
    int mn = (int)(c - scale + 0.5f);      // trunc toward zero == astype(int64)
    if (mn < 0) mn = 0;
    int mx = (int)(c + scale + 0.5f);
    if (mx > in_size) mx = in_size;
    int sz = mx - mn; if (sz > KS) sz = KS;

    float w[KS];
    float s = 0.0f;
#pragma unroll
    for (int j = 0; j < KS; ++j) {
        float v = 1.0f - fminf(fabsf(((float)(j + mn) - c + 0.5f) * invscale), 1.0f);
        v = (j < sz) ? v : 0.0f;
        w[j] = v;
        s += v;
    }
#pragma unroll
    for (int j = 0; j < KS; ++j) w[j] /= s;   // exact divide, once per entry

#pragma unroll
    for (int j = 0; j < KS; ++j) ws[base_off + j] = w[j];
    ((int*)ws)[base_off + 5] = mn;
    ws[base_off + 6] = 0.0f;
    ws[base_off + 7] = 0.0f;
}

__global__ __launch_bounds__(256) void gather_kernel(
    const float* __restrict__ in, const float* __restrict__ ws,
    float* __restrict__ out)
{
    const int total = BC * OH * OW;
    int t = blockIdx.x * blockDim.x + threadIdx.x;
    if (t >= total) return;

    const int ox = t % OW;
    const int r  = t / OW;
    const int oy = r % OH;
    const int bc = r / OH;

    // x-weight row: two coalesced float4 loads
    const float4* px = (const float4*)(ws + XTAB(ox));
    float4 xa = px[0], xb = px[1];
    const float wx0 = xa.x, wx1 = xa.y, wx2 = xa.z, wx3 = xa.w, wx4 = xb.x;
    const int   xmin = __float_as_int(xb.y);

    const float4* py = (const float4*)(ws + YTAB(oy));
    float4 ya = py[0], yb = py[1];
    const float wy0 = ya.x, wy1 = ya.y, wy2 = ya.z, wy3 = ya.w, wy4 = yb.x;
    const int   ymin = __float_as_int(yb.y);

    // clamped column indices (only the right edge can clamp; weights there are 0)
    int ix0 = xmin;
    int ix1 = xmin + 1; if (ix1 > IW - 1) ix1 = IW - 1;
    int ix2 = xmin + 2; if (ix2 > IW - 1) ix2 = IW - 1;
    int ix3 = xmin + 3; if (ix3 > IW - 1) ix3 = IW - 1;
    int ix4 = xmin + 4; if (ix4 > IW - 1) ix4 = IW - 1;

    const float* __restrict__ base = in + (size_t)bc * (IH * IW);
    float acc = 0.0f;
#pragma unroll
    for (int jy = 0; jy < KS; ++jy) {
        int iy = ymin + jy; if (iy > IH - 1) iy = IH - 1;
        const float* __restrict__ row = base + iy * IW;
        float h;
        h = row[ix0] * wx0;
        h = fmaf(row[ix1], wx1, h);
        h = fmaf(row[ix2], wx2, h);
        h = fmaf(row[ix3], wx3, h);
        h = fmaf(row[ix4], wx4, h);
        const float wy = (jy == 0) ? wy0 : (jy == 1) ? wy1 : (jy == 2) ? wy2
                       : (jy == 3) ? wy3 : wy4;
        acc = fmaf(h, wy, acc);
    }
    out[t] = acc;
}

extern "C" void kernel_launch(void* const* d_in, const int* in_sizes, int n_in,
                              void* d_out, int out_size, void* d_ws, size_t ws_size,
                              hipStream_t stream) {
    const float* in = (const float*)d_in[0];
    float* out = (float*)d_out;
    float* ws = (float*)d_ws;

    weights_kernel<<<1, 576, 0, stream>>>(ws);

    const int total = BC * OH * OW;   // 442272
    const int block = 256;
    const int grid = (total + block - 1) / block;   // 1728
    gather_kernel<<<grid, block, 0, stream>>>(in, ws, out);
}

// Round 3
// 9.835 us; speedup vs baseline: 1.7396x; 1.7396x over previous
//
#include <hip/hip_runtime.h>
#include <hip/hip_bf16.h>

// Fused antialiased bilinear resize (2,3,345,456) -> (2,3,271,272), fp32.
// Single kernel. Tap-count specialization for these exact scales:
//   x: 456->272, scale 1.6765, window span 3.353 -> at most 4 taps (tap3 masked)
//   y: 345->271, scale 1.2731, window span 2.546 -> at most 3 taps (tap2 masked)
// Weight normalization via v_rcp_f32 (rel err ~1e-7, threshold is 4.9e-2).

#define IW 456
#define IH 345
#define OW 272
#define OH 271
#define BC 6            // batch*channels = 2*3
#define TOTAL (BC * OH * OW)

__global__ __launch_bounds__(256) void resize2d_kernel(
    const float* __restrict__ in, float* __restrict__ out)
{
    int t = blockIdx.x * blockDim.x + threadIdx.x;
    if (t >= TOTAL) return;

    const int ox = t % OW;
    const int r  = t / OW;
    const int oy = r % OH;
    const int bc = r / OH;

    // ---- horizontal (x): 4 taps ----
    const float SX = (float)IW / (float)OW;   // 1.6764706
    const float RX = (float)OW / (float)IW;   // 0.59649123
    float cx = ((float)ox + 0.5f) * SX;
    int xmin = (int)(cx - SX + 0.5f);         // trunc == astype(int64)
    if (xmin < 0) xmin = 0;
    int xmax = (int)(cx + SX + 0.5f);
    if (xmax > IW) xmax = IW;
    const int xsz = xmax - xmin;              // 3 or 4

    float tx = (float)xmin - cx + 0.5f;
    float wx0 = 1.0f - fminf(fabsf(tx * RX), 1.0f);
    float wx1 = 1.0f - fminf(fabsf((tx + 1.0f) * RX), 1.0f);
    float wx2 = 1.0f - fminf(fabsf((tx + 2.0f) * RX), 1.0f);
    float wx3 = (xsz > 3) ? (1.0f - fminf(fabsf((tx + 3.0f) * RX), 1.0f)) : 0.0f;
    float rsx = __builtin_amdgcn_rcpf(wx0 + wx1 + wx2 + wx3);
    wx0 *= rsx; wx1 *= rsx; wx2 *= rsx; wx3 *= rsx;

    // ---- vertical (y): 3 taps ----
    const float SY = (float)IH / (float)OH;   // 1.2730627
    const float RY = (float)OH / (float)IH;   // 0.78550725
    float cy = ((float)oy + 0.5f) * SY;
    int ymin = (int)(cy - SY + 0.5f);
    if (ymin < 0) ymin = 0;
    int ymax = (int)(cy + SY + 0.5f);
    if (ymax > IH) ymax = IH;
    const int ysz = ymax - ymin;              // 2 or 3

    float ty = (float)ymin - cy + 0.5f;
    float wy0 = 1.0f - fminf(fabsf(ty * RY), 1.0f);
    float wy1 = 1.0f - fminf(fabsf((ty + 1.0f) * RY), 1.0f);
    float wy2 = (ysz > 2) ? (1.0f - fminf(fabsf((ty + 2.0f) * RY), 1.0f)) : 0.0f;
    float rsy = __builtin_amdgcn_rcpf(wy0 + wy1 + wy2);
    wy0 *= rsy; wy1 *= rsy; wy2 *= rsy;

    // ---- gather: 3 rows x 4 cols, horizontal then vertical (ref order) ----
    // edge clamps: xmin<=453 so xmin+2<=455 safe, xmin+3 may hit 456 (w=0);
    //              ymin<=343 so ymin+1<=344 safe, ymin+2 may hit 345 (w=0).
    const int ix3 = (xmin + 3 > IW - 1) ? (IW - 1) : (xmin + 3);
    const int iy2 = (ymin + 2 > IH - 1) ? (IH - 1) : (ymin + 2);

    const float* __restrict__ base = in + (size_t)bc * (IH * IW);
    const float* __restrict__ r0 = base + ymin * IW;
    const float* __restrict__ r1 = base + (ymin + 1) * IW;
    const float* __restrict__ r2 = base + iy2 * IW;

    float h0 = r0[xmin] * wx0;
    h0 = fmaf(r0[xmin + 1], wx1, h0);
    h0 = fmaf(r0[xmin + 2], wx2, h0);
    h0 = fmaf(r0[ix3],     wx3, h0);

    float h1 = r1[xmin] * wx0;
    h1 = fmaf(r1[xmin + 1], wx1, h1);
    h1 = fmaf(r1[xmin + 2], wx2, h1);
    h1 = fmaf(r1[ix3],     wx3, h1);

    float h2 = r2[xmin] * wx0;
    h2 = fmaf(r2[xmin + 1], wx1, h2);
    h2 = fmaf(r2[xmin + 2], wx2, h2);
    h2 = fmaf(r2[ix3],     wx3, h2);

    float acc = h0 * wy0;
    acc = fmaf(h1, wy1, acc);
    acc = fmaf(h2, wy2, acc);

    out[t] = acc;
}

extern "C" void kernel_launch(void* const* d_in, const int* in_sizes, int n_in,
                              void* d_out, int out_size, void* d_ws, size_t ws_size,
                              hipStream_t stream) {
    const float* in = (const float*)d_in[0];
    float* out = (float*)d_out;
    const int block = 256;
    const int grid = (TOTAL + block - 1) / block;   // 1728
    resize2d_kernel<<<grid, block, 0, stream>>>(in, out);
}